// Round 1
// baseline (821.737 us; speedup 1.0000x reference)
//
#include <hip/hip_runtime.h>
#include <cstddef>

// Problem constants (match reference)
#define N_NODES 100000
#define N_EDGES 1600000
#define E_TOT   (N_EDGES + N_NODES)   // edges + self loops = 1,700,000
#define IN_DIM  64
#define HIDDEN  128
#define Z_DIM   64

// ---------------- CSR build ----------------

__global__ __launch_bounds__(256) void init_cnt_k(int* cnt, int n) {
    int i = blockIdx.x * 256 + threadIdx.x;
    if (i < n) cnt[i] = 1;   // self loop
}

__global__ __launch_bounds__(256) void count_k(const int* __restrict__ dst, int* cnt, int e) {
    int i = blockIdx.x * 256 + threadIdx.x;
    if (i < e) atomicAdd(&cnt[dst[i]], 1);
}

__global__ __launch_bounds__(256) void dinv_k(const int* __restrict__ cnt, float* __restrict__ dinv, int n) {
    int i = blockIdx.x * 256 + threadIdx.x;
    if (i < n) dinv[i] = rsqrtf((float)cnt[i]);   // cnt >= 1 always
}

__global__ __launch_bounds__(256) void scan_block_k(const int* __restrict__ cnt, int* __restrict__ rowptr,
                                                    int* __restrict__ bsum, int n) {
    __shared__ int s[256];
    int tid = threadIdx.x;
    int i = blockIdx.x * 256 + tid;
    int v = (i < n) ? cnt[i] : 0;
    s[tid] = v;
    __syncthreads();
#pragma unroll
    for (int off = 1; off < 256; off <<= 1) {
        int t = (tid >= off) ? s[tid - off] : 0;
        __syncthreads();
        s[tid] += t;
        __syncthreads();
    }
    if (i < n) rowptr[i] = s[tid] - v;        // exclusive within block
    if (tid == 255) bsum[blockIdx.x] = s[255];
}

__global__ __launch_bounds__(512) void scan_bsum_k(int* bsum, int nb) {
    __shared__ int s[512];
    int tid = threadIdx.x;
    int v = (tid < nb) ? bsum[tid] : 0;
    s[tid] = v;
    __syncthreads();
#pragma unroll
    for (int off = 1; off < 512; off <<= 1) {
        int t = (tid >= off) ? s[tid - off] : 0;
        __syncthreads();
        s[tid] += t;
        __syncthreads();
    }
    if (tid < nb) bsum[tid] = s[tid] - v;     // exclusive
}

__global__ __launch_bounds__(256) void scan_add_k(int* __restrict__ rowptr, const int* __restrict__ bsum,
                                                  int* __restrict__ cursor, int n, int etot) {
    int i = blockIdx.x * 256 + threadIdx.x;
    if (i < n) {
        int val = rowptr[i] + bsum[blockIdx.x];
        rowptr[i] = val;
        cursor[i] = val;
    }
    if (i == 0) rowptr[n] = etot;
}

__global__ __launch_bounds__(256) void fill_k(const int* __restrict__ src, const int* __restrict__ dst,
                                              const float* __restrict__ dinv, int* cursor,
                                              int* __restrict__ col, float* __restrict__ nrm,
                                              int e, int n) {
    int i = blockIdx.x * 256 + threadIdx.x;
    if (i < e) {
        int s = src[i], d = dst[i];
        int p = atomicAdd(&cursor[d], 1);
        col[p] = s;
        nrm[p] = dinv[s] * dinv[d];
    } else if (i < e + n) {
        int v = i - e;
        int p = atomicAdd(&cursor[v], 1);
        col[p] = v;
        float dv = dinv[v];
        nrm[p] = dv * dv;
    }
}

// ---------------- Aggregation (gather): one wave per node ----------------

template <int DIM>
__global__ __launch_bounds__(256) void agg_k(const float* __restrict__ H, const int* __restrict__ rowptr,
                                             const int* __restrict__ col, const float* __restrict__ nrm,
                                             float* __restrict__ out, int n) {
    int node = (int)((blockIdx.x * 256 + threadIdx.x) >> 6);
    if (node >= n) return;
    int lane = threadIdx.x & 63;
    int beg = rowptr[node], end = rowptr[node + 1];
    if constexpr (DIM == 64) {
        float acc = 0.f;
        int j = beg;
        for (; j + 4 <= end; j += 4) {
            int   s0 = col[j + 0], s1 = col[j + 1], s2 = col[j + 2], s3 = col[j + 3];
            float w0 = nrm[j + 0], w1 = nrm[j + 1], w2 = nrm[j + 2], w3 = nrm[j + 3];
            float v0 = H[(size_t)s0 * 64 + lane];
            float v1 = H[(size_t)s1 * 64 + lane];
            float v2 = H[(size_t)s2 * 64 + lane];
            float v3 = H[(size_t)s3 * 64 + lane];
            acc += w0 * v0; acc += w1 * v1; acc += w2 * v2; acc += w3 * v3;
        }
        for (; j < end; j++) acc += nrm[j] * H[(size_t)col[j] * 64 + lane];
        out[(size_t)node * 64 + lane] = acc;
    } else {
        const float2* H2 = (const float2*)H;
        float2 acc; acc.x = 0.f; acc.y = 0.f;
        int j = beg;
        for (; j + 4 <= end; j += 4) {
            int   s0 = col[j + 0], s1 = col[j + 1], s2 = col[j + 2], s3 = col[j + 3];
            float w0 = nrm[j + 0], w1 = nrm[j + 1], w2 = nrm[j + 2], w3 = nrm[j + 3];
            float2 v0 = H2[(size_t)s0 * 64 + lane];
            float2 v1 = H2[(size_t)s1 * 64 + lane];
            float2 v2 = H2[(size_t)s2 * 64 + lane];
            float2 v3 = H2[(size_t)s3 * 64 + lane];
            acc.x += w0 * v0.x; acc.y += w0 * v0.y;
            acc.x += w1 * v1.x; acc.y += w1 * v1.y;
            acc.x += w2 * v2.x; acc.y += w2 * v2.y;
            acc.x += w3 * v3.x; acc.y += w3 * v3.y;
        }
        for (; j < end; j++) {
            float w = nrm[j];
            float2 v = H2[(size_t)col[j] * 64 + lane];
            acc.x += w * v.x; acc.y += w * v.y;
        }
        ((float2*)out)[(size_t)node * 64 + lane] = acc;
    }
}

// ---------------- Dense layer: C[M,F] = A[M,K] @ W[K,F] + b, optional ReLU ----------------
// Block = 256 threads, 32 nodes per block, K chunked by 64 to keep LDS <= ~41KB.

template <int K, int F, bool RELU>
__global__ __launch_bounds__(256) void gemm_k(const float* __restrict__ A, const float* __restrict__ W,
                                              const float* __restrict__ bias, float* __restrict__ C, int n) {
    constexpr int NT = 32;
    constexpr int KC = 64;
    constexpr int JF = F / 8;        // feats per thread (contiguous)
    constexpr int JV = JF / 4;       // float4s per thread
    __shared__ __align__(16) float Ws[KC * F];
    __shared__ __align__(16) float As[NT * (KC + 1)];

    int t = threadIdx.x;
    int m0 = blockIdx.x * NT;
    int m = t >> 3;
    int fg = t & 7;
    int f0 = fg * JF;

    float4 acc[JV];
#pragma unroll
    for (int j = 0; j < JV; j++) { acc[j].x = 0.f; acc[j].y = 0.f; acc[j].z = 0.f; acc[j].w = 0.f; }

    for (int kc = 0; kc < K; kc += KC) {
        // stage W chunk (rows kc..kc+KC-1, contiguous) and A tile
        for (int e = t; e < KC * F; e += 256) Ws[e] = W[kc * F + e];
        for (int e = t; e < NT * KC; e += 256) {
            int r = e >> 6;          // / KC
            int c = e & 63;          // % KC
            As[r * (KC + 1) + c] = A[(size_t)(m0 + r) * K + kc + c];
        }
        __syncthreads();
#pragma unroll 4
        for (int k = 0; k < KC; k++) {
            float a = As[m * (KC + 1) + k];
#pragma unroll
            for (int j = 0; j < JV; j++) {
                float4 w = *(const float4*)&Ws[k * F + f0 + 4 * j];
                acc[j].x += a * w.x;
                acc[j].y += a * w.y;
                acc[j].z += a * w.z;
                acc[j].w += a * w.w;
            }
        }
        __syncthreads();
    }

    size_t base = (size_t)(m0 + m) * F + f0;
#pragma unroll
    for (int j = 0; j < JV; j++) {
        float4 v = acc[j];
        v.x += bias[f0 + 4 * j + 0];
        v.y += bias[f0 + 4 * j + 1];
        v.z += bias[f0 + 4 * j + 2];
        v.w += bias[f0 + 4 * j + 3];
        if (RELU) {
            v.x = fmaxf(v.x, 0.f); v.y = fmaxf(v.y, 0.f);
            v.z = fmaxf(v.z, 0.f); v.w = fmaxf(v.w, 0.f);
        }
        *(float4*)&C[base + 4 * j] = v;
    }
}

// ---------------- launch ----------------

extern "C" void kernel_launch(void* const* d_in, const int* in_sizes, int n_in,
                              void* d_out, int out_size, void* d_ws, size_t ws_size,
                              hipStream_t stream) {
    const int N = N_NODES, E = N_EDGES, ETOT = E_TOT;

    const float* x    = (const float*)d_in[0];
    const int*   ei   = (const int*)d_in[1];
    const int*   srcA = ei;
    const int*   dstA = ei + E;
    const float* W1   = (const float*)d_in[2];
    const float* b1   = (const float*)d_in[3];
    const float* W2   = (const float*)d_in[4];
    const float* b2   = (const float*)d_in[5];
    const float* Wmu  = (const float*)d_in[6];
    const float* bmu  = (const float*)d_in[7];
    const float* Wlv  = (const float*)d_in[8];
    const float* blv  = (const float*)d_in[9];
    float* out = (float*)d_out;

    // workspace carve-out (~117 MB)
    char* ws = (char*)d_ws;
    size_t o = 0;
    auto alloc = [&](size_t bytes) -> void* {
        o = (o + 255) & ~(size_t)255;
        void* p = ws + o;
        o += bytes;
        return p;
    };
    int*   cnt    = (int*)alloc((size_t)N * 4);          // deg counts, later cursor
    int*   rowptr = (int*)alloc((size_t)(N + 1) * 4);
    float* dinv   = (float*)alloc((size_t)N * 4);
    int*   bsum   = (int*)alloc(512 * 4);
    int*   col    = (int*)alloc((size_t)ETOT * 4);
    float* nrm    = (float*)alloc((size_t)ETOT * 4);
    float* agg    = (float*)alloc((size_t)N * HIDDEN * 4);
    float* h      = (float*)alloc((size_t)N * HIDDEN * 4);
    (void)ws_size;

    const int gN = (N + 255) / 256;          // 391
    const int gE = (E + 255) / 256;          // 6250
    const int gT = (ETOT + 255) / 256;       // 6641
    const int gAgg = (N + 3) / 4;            // 25000 (4 nodes/block)
    const int gGemm = N / 32;                // 3125

    // CSR build
    init_cnt_k<<<gN, 256, 0, stream>>>(cnt, N);
    count_k<<<gE, 256, 0, stream>>>(dstA, cnt, E);
    dinv_k<<<gN, 256, 0, stream>>>(cnt, dinv, N);
    scan_block_k<<<gN, 256, 0, stream>>>(cnt, rowptr, bsum, N);
    scan_bsum_k<<<1, 512, 0, stream>>>(bsum, gN);
    scan_add_k<<<gN, 256, 0, stream>>>(rowptr, bsum, cnt /*cursor*/, N, ETOT);
    fill_k<<<gT, 256, 0, stream>>>(srcA, dstA, dinv, cnt, col, nrm, E, N);

    // layer 1: h = relu(Agg(x) @ W1 + b1)      (aggregate in 64-dim!)
    agg_k<64><<<gAgg, 256, 0, stream>>>(x, rowptr, col, nrm, agg, N);
    gemm_k<64, 128, true><<<gGemm, 256, 0, stream>>>(agg, W1, b1, h, N);

    // layer 2: h = relu(Agg(h) @ W2 + b2)
    agg_k<128><<<gAgg, 256, 0, stream>>>(h, rowptr, col, nrm, agg, N);
    gemm_k<128, 128, true><<<gGemm, 256, 0, stream>>>(agg, W2, b2, h, N);

    // heads: aggregate once, two GEMMs
    agg_k<128><<<gAgg, 256, 0, stream>>>(h, rowptr, col, nrm, agg, N);
    gemm_k<128, 64, false><<<gGemm, 256, 0, stream>>>(agg, Wmu, bmu, out, N);
    gemm_k<128, 64, false><<<gGemm, 256, 0, stream>>>(agg, Wlv, blv, out + (size_t)N * Z_DIM, N);
}